// Round 1
// baseline (94.243 us; speedup 1.0000x reference)
//
#include <hip/hip_runtime.h>
#include <math.h>

#define NN 4096
#define MM 4096
#define DIM 8
#define TASKS 8
#define BLOCK 256
#define CPT 4           // columns per thread (float4 store)
#define ROWS 32         // rows per block

// out[n,m] = (i[n]==ii[m]) ? exp(-0.5*sum_d(((x[n,d]-xx[m,d])*inv_s[t,d])^2)) * var[t] : 0
// where t = i[n] (== ii[m] when nonzero), inv_s/var from softplus of raw tables (diagonal only).
__global__ __launch_bounds__(BLOCK) void rbf_kernel(
    const float* __restrict__ x, const float* __restrict__ xx,
    const float* __restrict__ scale_raw, const float* __restrict__ var_raw,
    const int* __restrict__ i_idx, const int* __restrict__ ii_idx,
    float* __restrict__ out)
{
    __shared__ float s_inv[TASKS][DIM];
    __shared__ float s_var[TASKS];

    const int tid = threadIdx.x;
    if (tid < TASKS * DIM) {
        int t = tid / DIM, d = tid % DIM;
        float z = scale_raw[(t * TASKS + t) * DIM + d];   // diagonal scale[t][t][d]
        float sp = log1pf(__expf(z));                     // softplus
        s_inv[t][d] = 1.0f / sp;
    }
    if (tid < TASKS) {
        float z = var_raw[tid * TASKS + tid];             // diagonal variance[t][t]
        s_var[tid] = log1pf(__expf(z));
    }
    __syncthreads();

    const int col0 = blockIdx.x * (BLOCK * CPT) + tid * CPT;
    const int row0 = blockIdx.y * ROWS;

    // Per-column preload: task, var, inv_scale (a) and xx*inv_scale (b) -> registers.
    float a[CPT][DIM];
    float b[CPT][DIM];
    float vv[CPT];
    int   tc[CPT];
    #pragma unroll
    for (int k = 0; k < CPT; ++k) {
        const int c = col0 + k;
        const int t = ii_idx[c];
        tc[k] = t;
        vv[k] = s_var[t];
        float4 q0 = *(const float4*)&xx[c * DIM];
        float4 q1 = *(const float4*)&xx[c * DIM + 4];
        float xxv[DIM] = {q0.x, q0.y, q0.z, q0.w, q1.x, q1.y, q1.z, q1.w};
        #pragma unroll
        for (int d = 0; d < DIM; ++d) {
            float is = s_inv[t][d];
            a[k][d] = is;
            b[k][d] = xxv[d] * is;
        }
    }

    // Row loop: uniform x-row load (broadcast via L1), FMA chain, predicated exp, float4 store.
    for (int rr = 0; rr < ROWS; ++rr) {
        const int r = row0 + rr;
        const int t = i_idx[r];
        float4 p0 = *(const float4*)&x[r * DIM];
        float4 p1 = *(const float4*)&x[r * DIM + 4];
        float xr[DIM] = {p0.x, p0.y, p0.z, p0.w, p1.x, p1.y, p1.z, p1.w};

        float res[CPT];
        #pragma unroll
        for (int k = 0; k < CPT; ++k) {
            float dot = 0.0f;
            #pragma unroll
            for (int d = 0; d < DIM; ++d) {
                float rv = fmaf(xr[d], a[k][d], -b[k][d]);  // (x - xx) * inv_s
                dot = fmaf(rv, rv, dot);
            }
            float e = __expf(-0.5f * dot) * vv[k];
            res[k] = (t == tc[k]) ? e : 0.0f;
        }
        float4 o = {res[0], res[1], res[2], res[3]};
        *(float4*)&out[(size_t)r * MM + col0] = o;
    }
}

extern "C" void kernel_launch(void* const* d_in, const int* in_sizes, int n_in,
                              void* d_out, int out_size, void* d_ws, size_t ws_size,
                              hipStream_t stream) {
    const float* x         = (const float*)d_in[0];
    const float* xx        = (const float*)d_in[1];
    const float* scale_raw = (const float*)d_in[2];
    const float* var_raw   = (const float*)d_in[3];
    const int*   i_idx     = (const int*)d_in[4];
    const int*   ii_idx    = (const int*)d_in[5];
    float* out = (float*)d_out;

    dim3 grid(MM / (BLOCK * CPT), NN / ROWS);  // (4, 128) = 512 blocks
    dim3 block(BLOCK);
    rbf_kernel<<<grid, block, 0, stream>>>(x, xx, scale_raw, var_raw, i_idx, ii_idx, out);
}

// Round 2
// 93.116 us; speedup vs baseline: 1.0121x; 1.0121x over previous
//
#include <hip/hip_runtime.h>
#include <math.h>

#define NN 4096
#define MM 4096
#define DIM 8
#define TASKS 8
#define BLOCK 256
#define CPT 4           // columns per thread (float4 store)
#define ROWS 8          // rows per block (fully unrolled)

// out[n,m] = (i[n]==ii[m]) ? exp(-0.5*sum_d(((x[n,d]-xx[m,d])*inv_s[t,d])^2)) * var[t] : 0
// t = common task; inv_s/var from softplus of the diagonal entries of the raw tables.
__global__ __launch_bounds__(BLOCK) void rbf_kernel(
    const float* __restrict__ x, const float* __restrict__ xx,
    const float* __restrict__ scale_raw, const float* __restrict__ var_raw,
    const int* __restrict__ i_idx, const int* __restrict__ ii_idx,
    float* __restrict__ out)
{
    __shared__ float s_inv[TASKS][DIM];
    __shared__ float s_var[TASKS];

    const int tid = threadIdx.x;
    if (tid < TASKS * DIM) {
        int t = tid / DIM, d = tid % DIM;
        float z = scale_raw[(t * TASKS + t) * DIM + d];   // diagonal scale[t][t][d]
        s_inv[t][d] = 1.0f / log1pf(__expf(z));           // 1/softplus
    }
    if (tid < TASKS) {
        float z = var_raw[tid * TASKS + tid];             // diagonal variance[t][t]
        s_var[tid] = log1pf(__expf(z));
    }
    __syncthreads();

    const int col0 = blockIdx.x * (BLOCK * CPT) + tid * CPT;
    const int row0 = blockIdx.y * ROWS;

    // Per-column preload: task, var, inv_scale (a) and -xx*inv_scale (nb) -> registers.
    float a[CPT][DIM];
    float nb[CPT][DIM];
    float vv[CPT];
    int   tc[CPT];
    #pragma unroll
    for (int k = 0; k < CPT; ++k) {
        const int c = col0 + k;
        const int t = ii_idx[c];
        tc[k] = t;
        vv[k] = s_var[t];
        float4 q0 = *(const float4*)&xx[c * DIM];
        float4 q1 = *(const float4*)&xx[c * DIM + 4];
        float xxv[DIM] = {q0.x, q0.y, q0.z, q0.w, q1.x, q1.y, q1.z, q1.w};
        #pragma unroll
        for (int d = 0; d < DIM; ++d) {
            float is = s_inv[t][d];
            a[k][d]  = is;
            nb[k][d] = -xxv[d] * is;
        }
    }

    // Fully-unrolled row loop: uniform scalar loads get hoisted/batched by the
    // compiler; 8 float4 stores stream out back-to-back.
    #pragma unroll
    for (int rr = 0; rr < ROWS; ++rr) {
        const int r = row0 + rr;
        const int t = i_idx[r];
        float4 p0 = *(const float4*)&x[r * DIM];
        float4 p1 = *(const float4*)&x[r * DIM + 4];
        float xr[DIM] = {p0.x, p0.y, p0.z, p0.w, p1.x, p1.y, p1.z, p1.w};

        float res[CPT];
        #pragma unroll
        for (int k = 0; k < CPT; ++k) {
            float dot = 0.0f;
            #pragma unroll
            for (int d = 0; d < DIM; ++d) {
                float rv = fmaf(xr[d], a[k][d], nb[k][d]);  // (x - xx) * inv_s
                dot = fmaf(rv, rv, dot);
            }
            float e = __expf(-0.5f * dot) * vv[k];
            res[k] = (t == tc[k]) ? e : 0.0f;
        }
        float4 o = {res[0], res[1], res[2], res[3]};
        *(float4*)&out[(size_t)r * MM + col0] = o;
    }
}

extern "C" void kernel_launch(void* const* d_in, const int* in_sizes, int n_in,
                              void* d_out, int out_size, void* d_ws, size_t ws_size,
                              hipStream_t stream) {
    const float* x         = (const float*)d_in[0];
    const float* xx        = (const float*)d_in[1];
    const float* scale_raw = (const float*)d_in[2];
    const float* var_raw   = (const float*)d_in[3];
    const int*   i_idx     = (const int*)d_in[4];
    const int*   ii_idx    = (const int*)d_in[5];
    float* out = (float*)d_out;

    dim3 grid(MM / (BLOCK * CPT), NN / ROWS);  // (4, 512) = 2048 blocks
    dim3 block(BLOCK);
    rbf_kernel<<<grid, block, 0, stream>>>(x, xx, scale_raw, var_raw, i_idx, ii_idx, out);
}